// Round 7
// baseline (1252.848 us; speedup 1.0000x reference)
//
#include <hip/hip_runtime.h>
#include <cmath>

#define NB 512
#define SEQ 301
#define ATT_SCALE 0.25f

using f32x4  = __attribute__((ext_vector_type(4))) float;
using s16x4  = __attribute__((ext_vector_type(4))) short;

__device__ __forceinline__ unsigned short f2bf(float f) {
  unsigned int u = __builtin_bit_cast(unsigned int, f);
  u += 0x7fffu + ((u >> 16) & 1u);
  return (unsigned short)(u >> 16);
}

__device__ __forceinline__ s16x4 pk4(float4 v) {
  s16x4 t;
  t.x = (short)f2bf(v.x); t.y = (short)f2bf(v.y);
  t.z = (short)f2bf(v.z); t.w = (short)f2bf(v.w);
  return t;
}

__device__ __forceinline__ f32x4 mm16(s16x4 a, s16x4 b, f32x4 c) {
  return __builtin_amdgcn_mfma_f32_16x16x16bf16_1k(a, b, c, 0, 0, 0);
}

// ---------------- K1: SSE gate
__global__ __launch_bounds__(64) void k_sse(const float* __restrict__ xin,
    const float* __restrict__ sw, const float* __restrict__ sb, float* __restrict__ xs) {
  int blk = blockIdx.x; int b = blk / 25, p = blk % 25; int lane = threadIdx.x;
  const float* src = xin + (size_t)b*7500 + p*300;
  float s = 0.f;
  for (int c = lane; c < 300; c += 64) s += src[c]*sw[c];
  #pragma unroll
  for (int o = 32; o > 0; o >>= 1) s += __shfl_down(s, o, 64);
  s = __shfl(s, 0, 64);
  float sq = 1.f/(1.f + __expf(-(s + sb[0])));
  float* dst = xs + (size_t)b*7500 + p*300;
  for (int c = lane; c < 300; c += 64) dst[c] = src[c]*sq;
}

// ---------------- K2: fused conv1+conv2 (MFMA, conv1 output in LDS only)
__global__ __launch_bounds__(256) void k_conv12(const float* __restrict__ xs,
    const float* __restrict__ w1c, const float* __restrict__ b1c,
    const float* __restrict__ w2c, const float* __restrict__ b2c,
    float* __restrict__ c2) {
  int blk = blockIdx.x; int b = blk >> 2; int chunk = blk & 3;
  int w0 = chunk*73;
  int tid = threadIdx.x;
  int lane = tid & 63, wv = tid >> 6;
  int lm = lane & 15, lq = lane >> 4;
  __shared__ unsigned short xss[32*88];
  __shared__ unsigned short c1s[84*148];
  __shared__ unsigned short wt_s[96*148];

  const float* src = xs + (size_t)b*7500;
  for (int i = tid; i < 2025; i += 256) {
    int p = i/81, c = i - p*81;
    xss[p*88 + c] = f2bf(src[p*300 + w0 + c]);
  }
  for (int i = tid; i < 7*88; i += 256) xss[25*88 + i] = 0;
  for (int i = tid; i < 25*7; i += 256) { int p = i/7, c = 81 + i%7; xss[p*88 + c] = 0; }
  for (int i = tid; i < 9*148; i += 256) c1s[75*148 + i] = 0;
  for (int i = tid; i < 13824; i += 256) {
    int kw_ = i/4608, rem = i - kw_*4608;
    int o2 = rem/144, k = rem - o2*144;
    int ci = k/9, r_ = k - ci*9;
    wt_s[(kw_*32 + o2)*148 + k] = f2bf(w2c[o2*432 + ci*27 + r_*3 + kw_]);
  }

  s16x4 Af[4]; int P[4][4]; float bv[4];
  #pragma unroll
  for (int r = 0; r < 4; ++r) bv[r] = b1c[lq*4 + r];
  #pragma unroll
  for (int kc = 0; kc < 4; ++kc) {
    short e[4];
    #pragma unroll
    for (int j = 0; j < 4; ++j) {
      int k = kc*16 + lq*4 + j;
      float wf = (k < 63) ? w1c[lm*63 + k] : 0.f;
      e[j] = (short)f2bf(wf);
      int r_ = k/7, kw_ = k - r_*7;
      int kd = r_/3, kh = r_ - kd*3;
      P[kc][j] = (kd*5 + kh)*88 + kw_;
    }
    s16x4 a; a.x = e[0]; a.y = e[1]; a.z = e[2]; a.w = e[3];
    Af[kc] = a;
  }
  __syncthreads();

  for (int idx = wv; idx < 45; idx += 4) {
    int dh = idx/5, pt = idx - dh*5;
    int d0 = dh/3, h0 = dh - d0*3;
    int base = (d0*5 + h0)*88 + pt*16 + lm;
    f32x4 acc = {bv[0], bv[1], bv[2], bv[3]};
    #pragma unroll
    for (int kc = 0; kc < 4; ++kc) {
      s16x4 Bf;
      Bf.x = (short)xss[base + P[kc][0]];
      Bf.y = (short)xss[base + P[kc][1]];
      Bf.z = (short)xss[base + P[kc][2]];
      Bf.w = (short)xss[base + P[kc][3]];
      acc = mm16(Af[kc], Bf, acc);
    }
    int lw = pt*16 + lm;
    if (lw < 75) {
      unsigned short* dst = c1s + lw*148 + dh;
      #pragma unroll
      for (int r = 0; r < 4; ++r)
        dst[(lq*4 + r)*9] = f2bf(fmaxf(acc[r], 0.f));
    }
  }
  __syncthreads();

  float bvo0 = b2c[lm], bvo1 = b2c[16 + lm];
  for (int task = wv; task < 10; task += 4) {
    int pt = task >> 1, ot = task & 1;
    float bb = ot ? bvo1 : bvo0;
    f32x4 acc = {bb, bb, bb, bb};
    #pragma unroll
    for (int kw_ = 0; kw_ < 3; ++kw_) {
      int rowb = (pt*16 + lm + kw_)*148;
      int wrow = (kw_*32 + ot*16 + lm)*148;
      #pragma unroll
      for (int kc = 0; kc < 9; ++kc) {
        s16x4 Aw = *(const s16x4*)&c1s[rowb + kc*16 + lq*4];
        s16x4 Bw = *(const s16x4*)&wt_s[wrow + kc*16 + lq*4];
        acc = mm16(Aw, Bw, acc);
      }
    }
    float* dst = c2 + (size_t)b*9344 + (ot*16 + lm)*292;
    #pragma unroll
    for (int r = 0; r < 4; ++r) {
      int w2l = pt*16 + lq*4 + r;
      if (w2l < 73) dst[w0 + w2l] = fmaxf(acc[r], 0.f);
    }
  }
}

// ---------------- K4: dense1 as MFMA thin GEMM: y[512x64] = c2[512x9344] @ w^T + b
// 32 blocks x 16 batches; wave wv owns n-tile nt=wv over full K (584 steps of 16).
__global__ __launch_bounds__(256) void k_dense1(const float* __restrict__ c2,
    const float* __restrict__ w, const float* __restrict__ bias, float* __restrict__ y) {
  int b0 = blockIdx.x * 16;
  int tid = threadIdx.x;
  int lane = tid & 63; int nt = tid >> 6;
  int lm = lane & 15, lq = lane >> 4;
  const float* arow = c2 + (size_t)(b0 + lm)*9344;     // A: m = batch = lm
  const float* brow = w + (size_t)(nt*16 + lm)*9344;   // B: n = nt*16+lm
  f32x4 acc = {0.f, 0.f, 0.f, 0.f};
  #pragma unroll 4
  for (int ks = 0; ks < 584; ++ks) {
    int koff = ks*16 + lq*4;
    s16x4 af = pk4(*(const float4*)(arow + koff));
    s16x4 bf = pk4(*(const float4*)(brow + koff));
    acc = mm16(af, bf, acc);
  }
  float bb = bias[nt*16 + lm];
  // D: row m = batch lq*4+r, col n = lm (within nt tile)
  #pragma unroll
  for (int r = 0; r < 4; ++r)
    y[(size_t)(b0 + lq*4 + r)*64 + nt*16 + lm] = acc[r] + bb;
}

// ---------------- K5: patch embed + cls + pos
__global__ __launch_bounds__(256) void k_patch(const float* __restrict__ xs,
    const float* __restrict__ pw, const float* __restrict__ pb,
    const float* __restrict__ cls, const float* __restrict__ pos, float* __restrict__ x) {
  int row = blockIdx.x*4 + threadIdx.y;
  int b = row/SEQ; int s = row%SEQ; int d = threadIdx.x;
  float acc;
  if (s == 0) {
    acc = cls[d] + pos[d];
  } else {
    acc = pb[d] + pos[s*64 + d];
    const float* patch = xs + (size_t)b*7500 + (size_t)(s-1)*25;
    const float* wr = pw + d*25;
    #pragma unroll
    for (int p = 0; p < 25; ++p) acc += patch[p]*wr[p];
  }
  x[(size_t)row*64 + d] = acc;
}

// ---------------- K6: fused LN1 + QKV projection (MFMA), one block per batch b
__global__ __launch_bounds__(256) void k_qkv(const float* __restrict__ x,
    const float* __restrict__ g, const float* __restrict__ bt,
    const float* __restrict__ qkvw,
    unsigned short* __restrict__ q_g, unsigned short* __restrict__ k_g,
    unsigned short* __restrict__ vt_g) {
  int b = blockIdx.x;
  int tid = threadIdx.x;
  int lane = tid & 63, wv = tid >> 6;
  int lm = lane & 15, lq = lane >> 4;
  __shared__ unsigned short xn_s[304*68];

  for (int rr = tid; rr < 304; rr += 256) {
    int src = rr < 301 ? rr : 300;
    const float4* xp = (const float4*)(x + ((size_t)b*SEQ + src)*64);
    float4 xv[16];
    #pragma unroll
    for (int i = 0; i < 16; ++i) xv[i] = xp[i];
    float m = 0.f;
    #pragma unroll
    for (int i = 0; i < 16; ++i) m += xv[i].x + xv[i].y + xv[i].z + xv[i].w;
    m *= (1.f/64.f);
    float var = 0.f;
    #pragma unroll
    for (int i = 0; i < 16; ++i) {
      float a = xv[i].x-m, bb = xv[i].y-m, c = xv[i].z-m, dd = xv[i].w-m;
      var += a*a + bb*bb + c*c + dd*dd;
    }
    float rs = rsqrtf(var*(1.f/64.f) + 1e-5f);
    const float4* g4 = (const float4*)g;
    const float4* b4 = (const float4*)bt;
    #pragma unroll
    for (int i = 0; i < 16; ++i) {
      float4 gg = g4[i]; float4 bb = b4[i];
      float e0 = (xv[i].x-m)*rs*gg.x + bb.x;
      float e1 = (xv[i].y-m)*rs*gg.y + bb.y;
      float e2 = (xv[i].z-m)*rs*gg.z + bb.z;
      float e3 = (xv[i].w-m)*rs*gg.w + bb.w;
      unsigned int u0 = (unsigned int)f2bf(e0) | ((unsigned int)f2bf(e1) << 16);
      unsigned int u1 = (unsigned int)f2bf(e2) | ((unsigned int)f2bf(e3) << 16);
      *(uint2*)&xn_s[rr*68 + i*4] = make_uint2(u0, u1);
    }
  }
  __syncthreads();

  s16x4 Bf[3][4];
  int jidx[3];
  #pragma unroll
  for (int jj = 0; jj < 3; ++jj) {
    int j = wv*3 + jj; jidx[jj] = j;
    float scale = (j < 4) ? ATT_SCALE : 1.f;
    #pragma unroll
    for (int c = 0; c < 4; ++c) {
      float4 wf = *(const float4*)(qkvw + (size_t)(j*16 + lm)*64 + c*16 + lq*4);
      s16x4 bfv;
      bfv.x = (short)f2bf(wf.x*scale); bfv.y = (short)f2bf(wf.y*scale);
      bfv.z = (short)f2bf(wf.z*scale); bfv.w = (short)f2bf(wf.w*scale);
      Bf[jj][c] = bfv;
    }
  }
  for (int rt = 0; rt < 19; ++rt) {
    s16x4 Af[4];
    #pragma unroll
    for (int c = 0; c < 4; ++c)
      Af[c] = *(const s16x4*)&xn_s[(rt*16 + lm)*68 + c*16 + lq*4];
    #pragma unroll
    for (int jj = 0; jj < 3; ++jj) {
      int j = jidx[jj]; int h = j & 3; int type = j >> 2;
      if (type < 2) {
        f32x4 acc = {0.f,0.f,0.f,0.f};
        #pragma unroll
        for (int c = 0; c < 4; ++c) acc = mm16(Bf[jj][c], Af[c], acc);
        unsigned short* dst = (type == 0 ? q_g : k_g) + (size_t)(b*4 + h)*304*16;
        unsigned int u0 = (unsigned int)f2bf(acc[0]) | ((unsigned int)f2bf(acc[1]) << 16);
        unsigned int u1 = (unsigned int)f2bf(acc[2]) | ((unsigned int)f2bf(acc[3]) << 16);
        *(uint2*)&dst[(rt*16 + lm)*16 + lq*4] = make_uint2(u0, u1);
      } else {
        f32x4 acc = {0.f,0.f,0.f,0.f};
        #pragma unroll
        for (int c = 0; c < 4; ++c) acc = mm16(Af[c], Bf[jj][c], acc);
        unsigned int u0 = (unsigned int)f2bf(acc[0]) | ((unsigned int)f2bf(acc[1]) << 16);
        unsigned int u1 = (unsigned int)f2bf(acc[2]) | ((unsigned int)f2bf(acc[3]) << 16);
        *(uint2*)&vt_g[((size_t)(b*4 + h)*16 + lm)*304 + rt*16 + lq*4] = make_uint2(u0, u1);
      }
    }
  }
}

// ---------------- K7: MFMA attention, one block per (b,h)
__global__ __launch_bounds__(256) void k_attn(
    const unsigned short* __restrict__ q_g, const unsigned short* __restrict__ k_g,
    const unsigned short* __restrict__ vt_g, float* __restrict__ ao) {
  int bh = blockIdx.x; int b = bh >> 2, h = bh & 3;
  int tid = threadIdx.x;
  int lane = tid & 63, wv = tid >> 6;
  int lm = lane & 15, lq = lane >> 4;
  __shared__ unsigned short Ks[304*20];
  __shared__ unsigned short Qs[304*20];
  __shared__ unsigned short Vts[16*328];

  for (int i = tid; i < 304; i += 256) {
    const float4* kp = (const float4*)(k_g + ((size_t)bh*304 + i)*16);
    float4 a = kp[0], bb = kp[1];
    float2* d0 = (float2*)&Ks[i*20];
    d0[0] = make_float2(a.x, a.y);  d0[1] = make_float2(a.z, a.w);
    d0[2] = make_float2(bb.x, bb.y); d0[3] = make_float2(bb.z, bb.w);
    const float4* qp = (const float4*)(q_g + ((size_t)bh*304 + i)*16);
    float4 c = qp[0], dd = qp[1];
    float2* d1 = (float2*)&Qs[i*20];
    d1[0] = make_float2(c.x, c.y);  d1[1] = make_float2(c.z, c.w);
    d1[2] = make_float2(dd.x, dd.y); d1[3] = make_float2(dd.z, dd.w);
  }
  for (int i = tid; i < 16*38; i += 256) {
    int d = i / 38, gr = i % 38;
    float4 v = *(const float4*)(vt_g + ((size_t)bh*16 + d)*304 + gr*8);
    *(float4*)&Vts[d*328 + gr*8] = v;
  }
  __syncthreads();

  for (int qt = wv; qt < 19; qt += 4) {
    s16x4 qb = *(const s16x4*)&Qs[(qt*16 + lm)*20 + lq*4];
    f32x4 o = {0.f,0.f,0.f,0.f};
    float lsum = 0.f;
    #pragma unroll 2
    for (int kt = 0; kt < 18; ++kt) {
      s16x4 ka = *(const s16x4*)&Ks[(kt*16 + lm)*20 + lq*4];
      f32x4 zero = {0.f,0.f,0.f,0.f};
      f32x4 st = mm16(ka, qb, zero);
      float p0 = __expf(st[0]), p1 = __expf(st[1]), p2 = __expf(st[2]), p3 = __expf(st[3]);
      lsum += (p0 + p1) + (p2 + p3);
      s16x4 pa;
      pa.x = (short)f2bf(p0); pa.y = (short)f2bf(p1);
      pa.z = (short)f2bf(p2); pa.w = (short)f2bf(p3);
      s16x4 vb = *(const s16x4*)&Vts[lm*328 + kt*16 + lq*4];
      o = mm16(pa, vb, o);
    }
    {
      const int kt = 18;
      s16x4 ka = *(const s16x4*)&Ks[(kt*16 + lm)*20 + lq*4];
      f32x4 zero = {0.f,0.f,0.f,0.f};
      f32x4 st = mm16(ka, qb, zero);
      int kbase = kt*16 + lq*4;
      float p0 = (kbase + 0 < SEQ) ? __expf(st[0]) : 0.f;
      float p1 = (kbase + 1 < SEQ) ? __expf(st[1]) : 0.f;
      float p2 = (kbase + 2 < SEQ) ? __expf(st[2]) : 0.f;
      float p3 = (kbase + 3 < SEQ) ? __expf(st[3]) : 0.f;
      lsum += (p0 + p1) + (p2 + p3);
      s16x4 pa;
      pa.x = (short)f2bf(p0); pa.y = (short)f2bf(p1);
      pa.z = (short)f2bf(p2); pa.w = (short)f2bf(p3);
      s16x4 vb = *(const s16x4*)&Vts[lm*328 + kt*16 + lq*4];
      o = mm16(pa, vb, o);
    }
    lsum += __shfl_xor(lsum, 16, 64);
    lsum += __shfl_xor(lsum, 32, 64);
    float linv = 1.f / lsum;
    #pragma unroll
    for (int r = 0; r < 4; ++r) {
      int q = qt*16 + lq*4 + r;
      float lr = __shfl(linv, lq*4 + r, 64);
      if (q < SEQ) ao[((size_t)b*SEQ + q)*64 + h*16 + lm] = o[r] * lr;
    }
  }
}

// ---------------- K8: fused attn-out proj (MFMA) + residual + LN2 + FF + residual
__global__ __launch_bounds__(64) void k_post(const float* __restrict__ ao,
    const float* __restrict__ w, const float* __restrict__ bias,
    const float* __restrict__ g, const float* __restrict__ bt,
    const float* __restrict__ w1, const float* __restrict__ b1,
    const float* __restrict__ w2, const float* __restrict__ b2,
    float* __restrict__ x) {
  int b = blockIdx.x >> 2; int w0 = blockIdx.x & 3;
  int lane = threadIdx.x;
  int lm = lane & 15, lq = lane >> 4;

  s16x4 Bf[4][4];
  #pragma unroll
  for (int nt = 0; nt < 4; ++nt) {
    #pragma unroll
    for (int c = 0; c < 4; ++c) {
      float4 wf = *(const float4*)(w + (size_t)(nt*16 + lm)*64 + c*16 + lq*4);
      s16x4 t;
      t.x = (short)f2bf(wf.x); t.y = (short)f2bf(wf.y);
      t.z = (short)f2bf(wf.z); t.w = (short)f2bf(wf.w);
      Bf[nt][c] = t;
    }
  }
  float biasv[4], gv[4], btv[4], b2v[4];
  float w1r[8][4], w2r[4][8];
  #pragma unroll
  for (int nt = 0; nt < 4; ++nt) {
    biasv[nt] = bias[nt*16 + lm];
    gv[nt]    = g[nt*16 + lm];
    btv[nt]   = bt[nt*16 + lm];
    b2v[nt]   = b2[nt*16 + lm];
    #pragma unroll
    for (int t = 0; t < 8; ++t) w2r[nt][t] = w2[(nt*16 + lm)*8 + t];
  }
  #pragma unroll
  for (int t = 0; t < 8; ++t)
    #pragma unroll
    for (int nt = 0; nt < 4; ++nt) w1r[t][nt] = w1[t*64 + nt*16 + lm];

  for (int rt = w0; rt < 19; rt += 4) {
    int rsrc = rt*16 + lm; if (rsrc > 300) rsrc = 300;
    const float* arow = ao + ((size_t)b*SEQ + rsrc)*64;
    f32x4 acc[4];
    #pragma unroll
    for (int nt = 0; nt < 4; ++nt)
      acc[nt] = (f32x4){biasv[nt], biasv[nt], biasv[nt], biasv[nt]};
    #pragma unroll
    for (int c = 0; c < 4; ++c) {
      float4 av = *(const float4*)(arow + c*16 + lq*4);
      s16x4 af;
      af.x = (short)f2bf(av.x); af.y = (short)f2bf(av.y);
      af.z = (short)f2bf(av.z); af.w = (short)f2bf(av.w);
      #pragma unroll
      for (int nt = 0; nt < 4; ++nt) acc[nt] = mm16(af, Bf[nt][c], acc[nt]);
    }
    int row0 = rt*16 + lq*4;
    float v[4][4];
    #pragma unroll
    for (int r = 0; r < 4; ++r) {
      int row = row0 + r; int rs2 = row > 300 ? 300 : row;
      const float* xr = x + ((size_t)b*SEQ + rs2)*64;
      #pragma unroll
      for (int nt = 0; nt < 4; ++nt) v[r][nt] = acc[nt][r] + xr[nt*16 + lm];
    }
    #pragma unroll
    for (int r = 0; r < 4; ++r) {
      float s = (v[r][0] + v[r][1]) + (v[r][2] + v[r][3]);
      s += __shfl_xor(s, 1, 64); s += __shfl_xor(s, 2, 64);
      s += __shfl_xor(s, 4, 64); s += __shfl_xor(s, 8, 64);
      float m = s * (1.f/64.f);
      float c0 = v[r][0]-m, c1 = v[r][1]-m, c2 = v[r][2]-m, c3 = v[r][3]-m;
      float s2 = (c0*c0 + c1*c1) + (c2*c2 + c3*c3);
      s2 += __shfl_xor(s2, 1, 64); s2 += __shfl_xor(s2, 2, 64);
      s2 += __shfl_xor(s2, 4, 64); s2 += __shfl_xor(s2, 8, 64);
      float rs = rsqrtf(s2*(1.f/64.f) + 1e-5f);
      float xn0 = c0*rs*gv[0] + btv[0];
      float xn1 = c1*rs*gv[1] + btv[1];
      float xn2 = c2*rs*gv[2] + btv[2];
      float xn3 = c3*rs*gv[3] + btv[3];
      float hg[8];
      #pragma unroll
      for (int t = 0; t < 8; ++t) {
        float p = xn0*w1r[t][0] + xn1*w1r[t][1] + xn2*w1r[t][2] + xn3*w1r[t][3];
        p += __shfl_xor(p, 1, 64); p += __shfl_xor(p, 2, 64);
        p += __shfl_xor(p, 4, 64); p += __shfl_xor(p, 8, 64);
        float a = p + b1[t];
        hg[t] = 0.5f*a*(1.f + erff(a*0.70710678f));
      }
      int row = row0 + r;
      if (row < SEQ) {
        float* xw = x + ((size_t)b*SEQ + row)*64;
        #pragma unroll
        for (int nt = 0; nt < 4; ++nt) {
          float o = 0.f;
          #pragma unroll
          for (int t = 0; t < 8; ++t) o += hg[t]*w2r[nt][t];
          xw[nt*16 + lm] = v[r][nt] + o + b2v[nt];
        }
      }
    }
  }
}

// ---------------- K10: head
__global__ __launch_bounds__(128) void k_head(const float* __restrict__ x,
    const float* __restrict__ y, const float* __restrict__ g, const float* __restrict__ bt,
    const float* __restrict__ hw, const float* __restrict__ hb, float* __restrict__ out) {
  int b = blockIdx.x; int t = threadIdx.x; int lane = t & 63; int wv = t >> 6;
  float v = (t < 64) ? x[(size_t)b*SEQ*64 + t] : y[(size_t)b*64 + t - 64];
  __shared__ float rbuf[2];
  __shared__ float z_s[128];
  float s = v;
  #pragma unroll
  for (int o = 32; o; o >>= 1) s += __shfl_down(s, o, 64);
  if (lane == 0) rbuf[wv] = s;
  __syncthreads();
  float m = (rbuf[0] + rbuf[1]) * (1.f/128.f);
  __syncthreads();
  float c = v - m;
  float s2 = c*c;
  #pragma unroll
  for (int o = 32; o; o >>= 1) s2 += __shfl_down(s2, o, 64);
  if (lane == 0) rbuf[wv] = s2;
  __syncthreads();
  float var = (rbuf[0] + rbuf[1]) * (1.f/128.f);
  z_s[t] = c * rsqrtf(var + 1e-5f) * g[t] + bt[t];
  __syncthreads();
  if (t < 16) {
    float a = hb[t];
    const float* wr = hw + t*128;
    #pragma unroll 8
    for (int j = 0; j < 128; ++j) a += z_s[j]*wr[j];
    out[(size_t)b*16 + t] = a;
  }
}

extern "C" void kernel_launch(void* const* d_in, const int* in_sizes, int n_in,
                              void* d_out, int out_size, void* d_ws, size_t ws_size,
                              hipStream_t stream) {
  const float* input      = (const float*)d_in[0];
  const float* sse_w      = (const float*)d_in[1];
  const float* sse_b      = (const float*)d_in[2];
  const float* conv1_w    = (const float*)d_in[3];
  const float* conv1_b    = (const float*)d_in[4];
  const float* conv2_w    = (const float*)d_in[5];
  const float* conv2_b    = (const float*)d_in[6];
  const float* dense1_w   = (const float*)d_in[7];
  const float* dense1_b   = (const float*)d_in[8];
  const float* patch_w    = (const float*)d_in[9];
  const float* patch_b    = (const float*)d_in[10];
  const float* cls_token  = (const float*)d_in[11];
  const float* pos_emb    = (const float*)d_in[12];
  const float* ln1_g      = (const float*)d_in[13];
  const float* ln1_b      = (const float*)d_in[14];
  const float* qkv_w      = (const float*)d_in[15];
  const float* attn_out_w = (const float*)d_in[16];
  const float* attn_out_b = (const float*)d_in[17];
  const float* ln2_g      = (const float*)d_in[18];
  const float* ln2_b      = (const float*)d_in[19];
  const float* ff1_w      = (const float*)d_in[20];
  const float* ff1_b      = (const float*)d_in[21];
  const float* ff2_w      = (const float*)d_in[22];
  const float* ff2_b      = (const float*)d_in[23];
  const float* head_ln_g  = (const float*)d_in[24];
  const float* head_ln_b  = (const float*)d_in[25];
  const float* head_w     = (const float*)d_in[26];
  const float* head_b     = (const float*)d_in[27];
  float* out = (float*)d_out;

  float* ws = (float*)d_ws;
  float* xs  = ws;                    // 3,840,000
  float* y   = xs + 3840000;          // 32,768
  float* x   = y + 32768;             // 9,863,168
  float* R   = x + 9863168;           // shared region
  float* c2  = R + 21676032;          // conv phase
  float* ao  = R;                     // transformer phase
  unsigned short* q_g  = (unsigned short*)(R + 9863168);
  unsigned short* k_g  = q_g + 9961472;
  unsigned short* vt_g = k_g + 9961472;

  k_sse   <<<NB*25, 64, 0, stream>>>(input, sse_w, sse_b, xs);
  k_conv12<<<NB*4, 256, 0, stream>>>(xs, conv1_w, conv1_b, conv2_w, conv2_b, c2);
  k_dense1<<<NB/16, 256, 0, stream>>>(c2, dense1_w, dense1_b, y);
  k_patch <<<NB*SEQ/4, dim3(64,4), 0, stream>>>(xs, patch_w, patch_b, cls_token, pos_emb, x);
  for (int i = 0; i < 5; ++i) {
    k_qkv <<<NB, 256, 0, stream>>>(x, ln1_g + i*64, ln1_b + i*64,
                                   qkv_w + (size_t)i*192*64, q_g, k_g, vt_g);
    k_attn<<<NB*4, 256, 0, stream>>>(q_g, k_g, vt_g, ao);
    k_post<<<NB*4, 64, 0, stream>>>(ao,
                 attn_out_w + (size_t)i*4096, attn_out_b + i*64,
                 ln2_g + i*64, ln2_b + i*64,
                 ff1_w + (size_t)i*512, ff1_b + i*8, ff2_w + (size_t)i*512, ff2_b + i*64, x);
  }
  k_head<<<NB, 128, 0, stream>>>(x, y, head_ln_g, head_ln_b, head_w, head_b, out);
}

// Round 8
// 1010.912 us; speedup vs baseline: 1.2393x; 1.2393x over previous
//
#include <hip/hip_runtime.h>
#include <cmath>

#define NB 512
#define SEQ 301
#define ATT_SCALE 0.25f

using f32x4  = __attribute__((ext_vector_type(4))) float;
using s16x4  = __attribute__((ext_vector_type(4))) short;

__device__ __forceinline__ unsigned short f2bf(float f) {
  unsigned int u = __builtin_bit_cast(unsigned int, f);
  u += 0x7fffu + ((u >> 16) & 1u);
  return (unsigned short)(u >> 16);
}

__device__ __forceinline__ s16x4 pk4(float4 v) {
  s16x4 t;
  t.x = (short)f2bf(v.x); t.y = (short)f2bf(v.y);
  t.z = (short)f2bf(v.z); t.w = (short)f2bf(v.w);
  return t;
}

__device__ __forceinline__ f32x4 mm16(s16x4 a, s16x4 b, f32x4 c) {
  return __builtin_amdgcn_mfma_f32_16x16x16bf16_1k(a, b, c, 0, 0, 0);
}

// ---------------- K1: SSE gate
__global__ __launch_bounds__(64) void k_sse(const float* __restrict__ xin,
    const float* __restrict__ sw, const float* __restrict__ sb, float* __restrict__ xs) {
  int blk = blockIdx.x; int b = blk / 25, p = blk % 25; int lane = threadIdx.x;
  const float* src = xin + (size_t)b*7500 + p*300;
  float s = 0.f;
  for (int c = lane; c < 300; c += 64) s += src[c]*sw[c];
  #pragma unroll
  for (int o = 32; o > 0; o >>= 1) s += __shfl_down(s, o, 64);
  s = __shfl(s, 0, 64);
  float sq = 1.f/(1.f + __expf(-(s + sb[0])));
  float* dst = xs + (size_t)b*7500 + p*300;
  for (int c = lane; c < 300; c += 64) dst[c] = src[c]*sq;
}

// ---------------- K2: fused conv1+conv2 (MFMA, conv1 output in LDS only)
__global__ __launch_bounds__(256) void k_conv12(const float* __restrict__ xs,
    const float* __restrict__ w1c, const float* __restrict__ b1c,
    const float* __restrict__ w2c, const float* __restrict__ b2c,
    float* __restrict__ c2) {
  int blk = blockIdx.x; int b = blk >> 2; int chunk = blk & 3;
  int w0 = chunk*73;
  int tid = threadIdx.x;
  int lane = tid & 63, wv = tid >> 6;
  int lm = lane & 15, lq = lane >> 4;
  __shared__ unsigned short xss[32*88];
  __shared__ unsigned short c1s[84*148];
  __shared__ unsigned short wt_s[96*148];

  const float* src = xs + (size_t)b*7500;
  for (int i = tid; i < 2025; i += 256) {
    int p = i/81, c = i - p*81;
    xss[p*88 + c] = f2bf(src[p*300 + w0 + c]);
  }
  for (int i = tid; i < 7*88; i += 256) xss[25*88 + i] = 0;
  for (int i = tid; i < 25*7; i += 256) { int p = i/7, c = 81 + i%7; xss[p*88 + c] = 0; }
  for (int i = tid; i < 9*148; i += 256) c1s[75*148 + i] = 0;
  for (int i = tid; i < 13824; i += 256) {
    int kw_ = i/4608, rem = i - kw_*4608;
    int o2 = rem/144, k = rem - o2*144;
    int ci = k/9, r_ = k - ci*9;
    wt_s[(kw_*32 + o2)*148 + k] = f2bf(w2c[o2*432 + ci*27 + r_*3 + kw_]);
  }

  s16x4 Af[4]; int P[4][4]; float bv[4];
  #pragma unroll
  for (int r = 0; r < 4; ++r) bv[r] = b1c[lq*4 + r];
  #pragma unroll
  for (int kc = 0; kc < 4; ++kc) {
    short e[4];
    #pragma unroll
    for (int j = 0; j < 4; ++j) {
      int k = kc*16 + lq*4 + j;
      float wf = (k < 63) ? w1c[lm*63 + k] : 0.f;
      e[j] = (short)f2bf(wf);
      int r_ = k/7, kw_ = k - r_*7;
      int kd = r_/3, kh = r_ - kd*3;
      P[kc][j] = (kd*5 + kh)*88 + kw_;
    }
    s16x4 a; a.x = e[0]; a.y = e[1]; a.z = e[2]; a.w = e[3];
    Af[kc] = a;
  }
  __syncthreads();

  for (int idx = wv; idx < 45; idx += 4) {
    int dh = idx/5, pt = idx - dh*5;
    int d0 = dh/3, h0 = dh - d0*3;
    int base = (d0*5 + h0)*88 + pt*16 + lm;
    f32x4 acc = {bv[0], bv[1], bv[2], bv[3]};
    #pragma unroll
    for (int kc = 0; kc < 4; ++kc) {
      s16x4 Bf;
      Bf.x = (short)xss[base + P[kc][0]];
      Bf.y = (short)xss[base + P[kc][1]];
      Bf.z = (short)xss[base + P[kc][2]];
      Bf.w = (short)xss[base + P[kc][3]];
      acc = mm16(Af[kc], Bf, acc);
    }
    int lw = pt*16 + lm;
    if (lw < 75) {
      unsigned short* dst = c1s + lw*148 + dh;
      #pragma unroll
      for (int r = 0; r < 4; ++r)
        dst[(lq*4 + r)*9] = f2bf(fmaxf(acc[r], 0.f));
    }
  }
  __syncthreads();

  float bvo0 = b2c[lm], bvo1 = b2c[16 + lm];
  for (int task = wv; task < 10; task += 4) {
    int pt = task >> 1, ot = task & 1;
    float bb = ot ? bvo1 : bvo0;
    f32x4 acc = {bb, bb, bb, bb};
    #pragma unroll
    for (int kw_ = 0; kw_ < 3; ++kw_) {
      int rowb = (pt*16 + lm + kw_)*148;
      int wrow = (kw_*32 + ot*16 + lm)*148;
      #pragma unroll
      for (int kc = 0; kc < 9; ++kc) {
        s16x4 Aw = *(const s16x4*)&c1s[rowb + kc*16 + lq*4];
        s16x4 Bw = *(const s16x4*)&wt_s[wrow + kc*16 + lq*4];
        acc = mm16(Aw, Bw, acc);
      }
    }
    float* dst = c2 + (size_t)b*9344 + (ot*16 + lm)*292;
    #pragma unroll
    for (int r = 0; r < 4; ++r) {
      int w2l = pt*16 + lq*4 + r;
      if (w2l < 73) dst[w0 + w2l] = fmaxf(acc[r], 0.f);
    }
  }
}

// ---------------- K4: dense1 split-K MFMA: part[kc][512][64] partials (no bias)
// grid = 32 m-tiles x 16 K-chunks; 4 waves/block, wave = one 16-wide n-tile.
__global__ __launch_bounds__(256) void k_dense1(const float* __restrict__ c2,
    const float* __restrict__ w, float* __restrict__ part) {
  int mt = blockIdx.x & 31;          // m-tile (16 batches)
  int kc = blockIdx.x >> 5;          // K-chunk 0..15
  int b0 = mt * 16;
  int tid = threadIdx.x;
  int lane = tid & 63; int nt = tid >> 6;
  int lm = lane & 15, lq = lane >> 4;
  int s0 = kc*36 + (kc < 8 ? kc : 8);       // start step
  int cnt = 36 + (kc < 8 ? 1 : 0);          // 37 for kc<8, else 36
  const float* arow = c2 + (size_t)(b0 + lm)*9344;
  const float* brow = w + (size_t)(nt*16 + lm)*9344;
  f32x4 acc = {0.f, 0.f, 0.f, 0.f};
  int koff = s0*16 + lq*4;
  #pragma unroll 4
  for (int i = 0; i < cnt; ++i, koff += 16) {
    s16x4 af = pk4(*(const float4*)(arow + koff));
    s16x4 bf = pk4(*(const float4*)(brow + koff));
    acc = mm16(af, bf, acc);
  }
  float* dst = part + (size_t)kc*32768;
  #pragma unroll
  for (int r = 0; r < 4; ++r)
    dst[(size_t)(b0 + lq*4 + r)*64 + nt*16 + lm] = acc[r];
}

// ---------------- K5: patch embed + cls + pos
__global__ __launch_bounds__(256) void k_patch(const float* __restrict__ xs,
    const float* __restrict__ pw, const float* __restrict__ pb,
    const float* __restrict__ cls, const float* __restrict__ pos, float* __restrict__ x) {
  int row = blockIdx.x*4 + threadIdx.y;
  int b = row/SEQ; int s = row%SEQ; int d = threadIdx.x;
  float acc;
  if (s == 0) {
    acc = cls[d] + pos[d];
  } else {
    acc = pb[d] + pos[s*64 + d];
    const float* patch = xs + (size_t)b*7500 + (size_t)(s-1)*25;
    const float* wr = pw + d*25;
    #pragma unroll
    for (int p = 0; p < 25; ++p) acc += patch[p]*wr[p];
  }
  x[(size_t)row*64 + d] = acc;
}

// ---------------- K6: fused LN1 + QKV projection (MFMA), one block per batch b
__global__ __launch_bounds__(256) void k_qkv(const float* __restrict__ x,
    const float* __restrict__ g, const float* __restrict__ bt,
    const float* __restrict__ qkvw,
    unsigned short* __restrict__ q_g, unsigned short* __restrict__ k_g,
    unsigned short* __restrict__ vt_g) {
  int b = blockIdx.x;
  int tid = threadIdx.x;
  int lane = tid & 63, wv = tid >> 6;
  int lm = lane & 15, lq = lane >> 4;
  __shared__ unsigned short xn_s[304*68];

  for (int rr = tid; rr < 304; rr += 256) {
    int src = rr < 301 ? rr : 300;
    const float4* xp = (const float4*)(x + ((size_t)b*SEQ + src)*64);
    float4 xv[16];
    #pragma unroll
    for (int i = 0; i < 16; ++i) xv[i] = xp[i];
    float m = 0.f;
    #pragma unroll
    for (int i = 0; i < 16; ++i) m += xv[i].x + xv[i].y + xv[i].z + xv[i].w;
    m *= (1.f/64.f);
    float var = 0.f;
    #pragma unroll
    for (int i = 0; i < 16; ++i) {
      float a = xv[i].x-m, bb = xv[i].y-m, c = xv[i].z-m, dd = xv[i].w-m;
      var += a*a + bb*bb + c*c + dd*dd;
    }
    float rs = rsqrtf(var*(1.f/64.f) + 1e-5f);
    const float4* g4 = (const float4*)g;
    const float4* b4 = (const float4*)bt;
    #pragma unroll
    for (int i = 0; i < 16; ++i) {
      float4 gg = g4[i]; float4 bb = b4[i];
      float e0 = (xv[i].x-m)*rs*gg.x + bb.x;
      float e1 = (xv[i].y-m)*rs*gg.y + bb.y;
      float e2 = (xv[i].z-m)*rs*gg.z + bb.z;
      float e3 = (xv[i].w-m)*rs*gg.w + bb.w;
      unsigned int u0 = (unsigned int)f2bf(e0) | ((unsigned int)f2bf(e1) << 16);
      unsigned int u1 = (unsigned int)f2bf(e2) | ((unsigned int)f2bf(e3) << 16);
      *(uint2*)&xn_s[rr*68 + i*4] = make_uint2(u0, u1);
    }
  }
  __syncthreads();

  s16x4 Bf[3][4];
  int jidx[3];
  #pragma unroll
  for (int jj = 0; jj < 3; ++jj) {
    int j = wv*3 + jj; jidx[jj] = j;
    float scale = (j < 4) ? ATT_SCALE : 1.f;
    #pragma unroll
    for (int c = 0; c < 4; ++c) {
      float4 wf = *(const float4*)(qkvw + (size_t)(j*16 + lm)*64 + c*16 + lq*4);
      s16x4 bfv;
      bfv.x = (short)f2bf(wf.x*scale); bfv.y = (short)f2bf(wf.y*scale);
      bfv.z = (short)f2bf(wf.z*scale); bfv.w = (short)f2bf(wf.w*scale);
      Bf[jj][c] = bfv;
    }
  }
  for (int rt = 0; rt < 19; ++rt) {
    s16x4 Af[4];
    #pragma unroll
    for (int c = 0; c < 4; ++c)
      Af[c] = *(const s16x4*)&xn_s[(rt*16 + lm)*68 + c*16 + lq*4];
    #pragma unroll
    for (int jj = 0; jj < 3; ++jj) {
      int j = jidx[jj]; int h = j & 3; int type = j >> 2;
      if (type < 2) {
        f32x4 acc = {0.f,0.f,0.f,0.f};
        #pragma unroll
        for (int c = 0; c < 4; ++c) acc = mm16(Bf[jj][c], Af[c], acc);
        unsigned short* dst = (type == 0 ? q_g : k_g) + (size_t)(b*4 + h)*304*16;
        unsigned int u0 = (unsigned int)f2bf(acc[0]) | ((unsigned int)f2bf(acc[1]) << 16);
        unsigned int u1 = (unsigned int)f2bf(acc[2]) | ((unsigned int)f2bf(acc[3]) << 16);
        *(uint2*)&dst[(rt*16 + lm)*16 + lq*4] = make_uint2(u0, u1);
      } else {
        f32x4 acc = {0.f,0.f,0.f,0.f};
        #pragma unroll
        for (int c = 0; c < 4; ++c) acc = mm16(Af[c], Bf[jj][c], acc);
        unsigned int u0 = (unsigned int)f2bf(acc[0]) | ((unsigned int)f2bf(acc[1]) << 16);
        unsigned int u1 = (unsigned int)f2bf(acc[2]) | ((unsigned int)f2bf(acc[3]) << 16);
        *(uint2*)&vt_g[((size_t)(b*4 + h)*16 + lm)*304 + rt*16 + lq*4] = make_uint2(u0, u1);
      }
    }
  }
}

// ---------------- K7: MFMA attention, one block per (b,h)
__global__ __launch_bounds__(256) void k_attn(
    const unsigned short* __restrict__ q_g, const unsigned short* __restrict__ k_g,
    const unsigned short* __restrict__ vt_g, float* __restrict__ ao) {
  int bh = blockIdx.x; int b = bh >> 2, h = bh & 3;
  int tid = threadIdx.x;
  int lane = tid & 63, wv = tid >> 6;
  int lm = lane & 15, lq = lane >> 4;
  __shared__ unsigned short Ks[304*20];
  __shared__ unsigned short Qs[304*20];
  __shared__ unsigned short Vts[16*328];

  for (int i = tid; i < 304; i += 256) {
    const float4* kp = (const float4*)(k_g + ((size_t)bh*304 + i)*16);
    float4 a = kp[0], bb = kp[1];
    float2* d0 = (float2*)&Ks[i*20];
    d0[0] = make_float2(a.x, a.y);  d0[1] = make_float2(a.z, a.w);
    d0[2] = make_float2(bb.x, bb.y); d0[3] = make_float2(bb.z, bb.w);
    const float4* qp = (const float4*)(q_g + ((size_t)bh*304 + i)*16);
    float4 c = qp[0], dd = qp[1];
    float2* d1 = (float2*)&Qs[i*20];
    d1[0] = make_float2(c.x, c.y);  d1[1] = make_float2(c.z, c.w);
    d1[2] = make_float2(dd.x, dd.y); d1[3] = make_float2(dd.z, dd.w);
  }
  for (int i = tid; i < 16*38; i += 256) {
    int d = i / 38, gr = i % 38;
    float4 v = *(const float4*)(vt_g + ((size_t)bh*16 + d)*304 + gr*8);
    *(float4*)&Vts[d*328 + gr*8] = v;
  }
  __syncthreads();

  for (int qt = wv; qt < 19; qt += 4) {
    s16x4 qb = *(const s16x4*)&Qs[(qt*16 + lm)*20 + lq*4];
    f32x4 o = {0.f,0.f,0.f,0.f};
    float lsum = 0.f;
    #pragma unroll 2
    for (int kt = 0; kt < 18; ++kt) {
      s16x4 ka = *(const s16x4*)&Ks[(kt*16 + lm)*20 + lq*4];
      f32x4 zero = {0.f,0.f,0.f,0.f};
      f32x4 st = mm16(ka, qb, zero);
      float p0 = __expf(st[0]), p1 = __expf(st[1]), p2 = __expf(st[2]), p3 = __expf(st[3]);
      lsum += (p0 + p1) + (p2 + p3);
      s16x4 pa;
      pa.x = (short)f2bf(p0); pa.y = (short)f2bf(p1);
      pa.z = (short)f2bf(p2); pa.w = (short)f2bf(p3);
      s16x4 vb = *(const s16x4*)&Vts[lm*328 + kt*16 + lq*4];
      o = mm16(pa, vb, o);
    }
    {
      const int kt = 18;
      s16x4 ka = *(const s16x4*)&Ks[(kt*16 + lm)*20 + lq*4];
      f32x4 zero = {0.f,0.f,0.f,0.f};
      f32x4 st = mm16(ka, qb, zero);
      int kbase = kt*16 + lq*4;
      float p0 = (kbase + 0 < SEQ) ? __expf(st[0]) : 0.f;
      float p1 = (kbase + 1 < SEQ) ? __expf(st[1]) : 0.f;
      float p2 = (kbase + 2 < SEQ) ? __expf(st[2]) : 0.f;
      float p3 = (kbase + 3 < SEQ) ? __expf(st[3]) : 0.f;
      lsum += (p0 + p1) + (p2 + p3);
      s16x4 pa;
      pa.x = (short)f2bf(p0); pa.y = (short)f2bf(p1);
      pa.z = (short)f2bf(p2); pa.w = (short)f2bf(p3);
      s16x4 vb = *(const s16x4*)&Vts[lm*328 + kt*16 + lq*4];
      o = mm16(pa, vb, o);
    }
    lsum += __shfl_xor(lsum, 16, 64);
    lsum += __shfl_xor(lsum, 32, 64);
    float linv = 1.f / lsum;
    #pragma unroll
    for (int r = 0; r < 4; ++r) {
      int q = qt*16 + lq*4 + r;
      float lr = __shfl(linv, lq*4 + r, 64);
      if (q < SEQ) ao[((size_t)b*SEQ + q)*64 + h*16 + lm] = o[r] * lr;
    }
  }
}

// ---------------- K8: fused attn-out proj (MFMA) + residual + LN2 + FF + residual
__global__ __launch_bounds__(64) void k_post(const float* __restrict__ ao,
    const float* __restrict__ w, const float* __restrict__ bias,
    const float* __restrict__ g, const float* __restrict__ bt,
    const float* __restrict__ w1, const float* __restrict__ b1,
    const float* __restrict__ w2, const float* __restrict__ b2,
    float* __restrict__ x) {
  int b = blockIdx.x >> 2; int w0 = blockIdx.x & 3;
  int lane = threadIdx.x;
  int lm = lane & 15, lq = lane >> 4;

  s16x4 Bf[4][4];
  #pragma unroll
  for (int nt = 0; nt < 4; ++nt) {
    #pragma unroll
    for (int c = 0; c < 4; ++c) {
      float4 wf = *(const float4*)(w + (size_t)(nt*16 + lm)*64 + c*16 + lq*4);
      s16x4 t;
      t.x = (short)f2bf(wf.x); t.y = (short)f2bf(wf.y);
      t.z = (short)f2bf(wf.z); t.w = (short)f2bf(wf.w);
      Bf[nt][c] = t;
    }
  }
  float biasv[4], gv[4], btv[4], b2v[4];
  float w1r[8][4], w2r[4][8];
  #pragma unroll
  for (int nt = 0; nt < 4; ++nt) {
    biasv[nt] = bias[nt*16 + lm];
    gv[nt]    = g[nt*16 + lm];
    btv[nt]   = bt[nt*16 + lm];
    b2v[nt]   = b2[nt*16 + lm];
    #pragma unroll
    for (int t = 0; t < 8; ++t) w2r[nt][t] = w2[(nt*16 + lm)*8 + t];
  }
  #pragma unroll
  for (int t = 0; t < 8; ++t)
    #pragma unroll
    for (int nt = 0; nt < 4; ++nt) w1r[t][nt] = w1[t*64 + nt*16 + lm];

  for (int rt = w0; rt < 19; rt += 4) {
    int rsrc = rt*16 + lm; if (rsrc > 300) rsrc = 300;
    const float* arow = ao + ((size_t)b*SEQ + rsrc)*64;
    f32x4 acc[4];
    #pragma unroll
    for (int nt = 0; nt < 4; ++nt)
      acc[nt] = (f32x4){biasv[nt], biasv[nt], biasv[nt], biasv[nt]};
    #pragma unroll
    for (int c = 0; c < 4; ++c) {
      float4 av = *(const float4*)(arow + c*16 + lq*4);
      s16x4 af;
      af.x = (short)f2bf(av.x); af.y = (short)f2bf(av.y);
      af.z = (short)f2bf(av.z); af.w = (short)f2bf(av.w);
      #pragma unroll
      for (int nt = 0; nt < 4; ++nt) acc[nt] = mm16(af, Bf[nt][c], acc[nt]);
    }
    int row0 = rt*16 + lq*4;
    float v[4][4];
    #pragma unroll
    for (int r = 0; r < 4; ++r) {
      int row = row0 + r; int rs2 = row > 300 ? 300 : row;
      const float* xr = x + ((size_t)b*SEQ + rs2)*64;
      #pragma unroll
      for (int nt = 0; nt < 4; ++nt) v[r][nt] = acc[nt][r] + xr[nt*16 + lm];
    }
    #pragma unroll
    for (int r = 0; r < 4; ++r) {
      float s = (v[r][0] + v[r][1]) + (v[r][2] + v[r][3]);
      s += __shfl_xor(s, 1, 64); s += __shfl_xor(s, 2, 64);
      s += __shfl_xor(s, 4, 64); s += __shfl_xor(s, 8, 64);
      float m = s * (1.f/64.f);
      float c0 = v[r][0]-m, c1 = v[r][1]-m, c2 = v[r][2]-m, c3 = v[r][3]-m;
      float s2 = (c0*c0 + c1*c1) + (c2*c2 + c3*c3);
      s2 += __shfl_xor(s2, 1, 64); s2 += __shfl_xor(s2, 2, 64);
      s2 += __shfl_xor(s2, 4, 64); s2 += __shfl_xor(s2, 8, 64);
      float rs = rsqrtf(s2*(1.f/64.f) + 1e-5f);
      float xn0 = c0*rs*gv[0] + btv[0];
      float xn1 = c1*rs*gv[1] + btv[1];
      float xn2 = c2*rs*gv[2] + btv[2];
      float xn3 = c3*rs*gv[3] + btv[3];
      float hg[8];
      #pragma unroll
      for (int t = 0; t < 8; ++t) {
        float p = xn0*w1r[t][0] + xn1*w1r[t][1] + xn2*w1r[t][2] + xn3*w1r[t][3];
        p += __shfl_xor(p, 1, 64); p += __shfl_xor(p, 2, 64);
        p += __shfl_xor(p, 4, 64); p += __shfl_xor(p, 8, 64);
        float a = p + b1[t];
        hg[t] = 0.5f*a*(1.f + erff(a*0.70710678f));
      }
      int row = row0 + r;
      if (row < SEQ) {
        float* xw = x + ((size_t)b*SEQ + row)*64;
        #pragma unroll
        for (int nt = 0; nt < 4; ++nt) {
          float o = 0.f;
          #pragma unroll
          for (int t = 0; t < 8; ++t) o += hg[t]*w2r[nt][t];
          xw[nt*16 + lm] = v[r][nt] + o + b2v[nt];
        }
      }
    }
  }
}

// ---------------- K10: head (sums dense1 split-K partials + bias inline)
__global__ __launch_bounds__(128) void k_head(const float* __restrict__ x,
    const float* __restrict__ part, const float* __restrict__ d1b,
    const float* __restrict__ g, const float* __restrict__ bt,
    const float* __restrict__ hw, const float* __restrict__ hb, float* __restrict__ out) {
  int b = blockIdx.x; int t = threadIdx.x; int lane = t & 63; int wv = t >> 6;
  float v;
  if (t < 64) {
    v = x[(size_t)b*SEQ*64 + t];
  } else {
    int o = t - 64;
    float acc = d1b[o];
    #pragma unroll
    for (int kc = 0; kc < 16; ++kc) acc += part[(size_t)kc*32768 + b*64 + o];
    v = acc;
  }
  __shared__ float rbuf[2];
  __shared__ float z_s[128];
  float s = v;
  #pragma unroll
  for (int o = 32; o; o >>= 1) s += __shfl_down(s, o, 64);
  if (lane == 0) rbuf[wv] = s;
  __syncthreads();
  float m = (rbuf[0] + rbuf[1]) * (1.f/128.f);
  __syncthreads();
  float c = v - m;
  float s2 = c*c;
  #pragma unroll
  for (int o = 32; o; o >>= 1) s2 += __shfl_down(s2, o, 64);
  if (lane == 0) rbuf[wv] = s2;
  __syncthreads();
  float var = (rbuf[0] + rbuf[1]) * (1.f/128.f);
  z_s[t] = c * rsqrtf(var + 1e-5f) * g[t] + bt[t];
  __syncthreads();
  if (t < 16) {
    float a = hb[t];
    const float* wr = hw + t*128;
    #pragma unroll 8
    for (int j = 0; j < 128; ++j) a += z_s[j]*wr[j];
    out[(size_t)b*16 + t] = a;
  }
}

extern "C" void kernel_launch(void* const* d_in, const int* in_sizes, int n_in,
                              void* d_out, int out_size, void* d_ws, size_t ws_size,
                              hipStream_t stream) {
  const float* input      = (const float*)d_in[0];
  const float* sse_w      = (const float*)d_in[1];
  const float* sse_b      = (const float*)d_in[2];
  const float* conv1_w    = (const float*)d_in[3];
  const float* conv1_b    = (const float*)d_in[4];
  const float* conv2_w    = (const float*)d_in[5];
  const float* conv2_b    = (const float*)d_in[6];
  const float* dense1_w   = (const float*)d_in[7];
  const float* dense1_b   = (const float*)d_in[8];
  const float* patch_w    = (const float*)d_in[9];
  const float* patch_b    = (const float*)d_in[10];
  const float* cls_token  = (const float*)d_in[11];
  const float* pos_emb    = (const float*)d_in[12];
  const float* ln1_g      = (const float*)d_in[13];
  const float* ln1_b      = (const float*)d_in[14];
  const float* qkv_w      = (const float*)d_in[15];
  const float* attn_out_w = (const float*)d_in[16];
  const float* attn_out_b = (const float*)d_in[17];
  const float* ln2_g      = (const float*)d_in[18];
  const float* ln2_b      = (const float*)d_in[19];
  const float* ff1_w      = (const float*)d_in[20];
  const float* ff1_b      = (const float*)d_in[21];
  const float* ff2_w      = (const float*)d_in[22];
  const float* ff2_b      = (const float*)d_in[23];
  const float* head_ln_g  = (const float*)d_in[24];
  const float* head_ln_b  = (const float*)d_in[25];
  const float* head_w     = (const float*)d_in[26];
  const float* head_b     = (const float*)d_in[27];
  float* out = (float*)d_out;

  float* ws = (float*)d_ws;
  float* xs  = ws;                    // 3,840,000 (dead after k_patch -> reused for part)
  float* part = ws;                   // 16*32768 = 524,288 floats (dense1 partials)
  float* y   = xs + 3840000;          // 32,768 (unused this round)
  float* x   = y + 32768;             // 9,863,168
  float* R   = x + 9863168;           // shared region
  float* c2  = R + 21676032;          // conv phase
  float* ao  = R;                     // transformer phase
  unsigned short* q_g  = (unsigned short*)(R + 9863168);
  unsigned short* k_g  = q_g + 9961472;
  unsigned short* vt_g = k_g + 9961472;

  k_sse   <<<NB*25, 64, 0, stream>>>(input, sse_w, sse_b, xs);
  k_conv12<<<NB*4, 256, 0, stream>>>(xs, conv1_w, conv1_b, conv2_w, conv2_b, c2);
  k_patch <<<NB*SEQ/4, dim3(64,4), 0, stream>>>(xs, patch_w, patch_b, cls_token, pos_emb, x);
  // xs is dead now; part overwrites it (stream-ordered after k_patch)
  k_dense1<<<512, 256, 0, stream>>>(c2, dense1_w, part);
  for (int i = 0; i < 5; ++i) {
    k_qkv <<<NB, 256, 0, stream>>>(x, ln1_g + i*64, ln1_b + i*64,
                                   qkv_w + (size_t)i*192*64, q_g, k_g, vt_g);
    k_attn<<<NB*4, 256, 0, stream>>>(q_g, k_g, vt_g, ao);
    k_post<<<NB*4, 64, 0, stream>>>(ao,
                 attn_out_w + (size_t)i*4096, attn_out_b + i*64,
                 ln2_g + i*64, ln2_b + i*64,
                 ff1_w + (size_t)i*512, ff1_b + i*8, ff2_w + (size_t)i*512, ff2_b + i*64, x);
  }
  k_head<<<NB, 128, 0, stream>>>(x, part, dense1_b, head_ln_g, head_ln_b, head_w, head_b, out);
}